// Round 3
// baseline (480.718 us; speedup 1.0000x reference)
//
#include <hip/hip_runtime.h>
#include <math.h>

#define NB 4
#define NT 4096
#define ND 1024
#define NS 16     // NUM_EXPERTS * NUM_SLOTS
#define NE 8
#define NF 4096

__device__ __forceinline__ float gelu(float v) {
  return 0.5f * v * (1.f + erff(v * 0.70710678118654752f));
}
__device__ __forceinline__ void fma4(float4& a, float s, const float4& v) {
  a.x += s * v.x; a.y += s * v.y; a.z += s * v.z; a.w += s * v.w;
}
__device__ __forceinline__ float4 ld4(const float* p) {
  return *reinterpret_cast<const float4*>(p);
}

// ---- stage A: logits[t][n] = dot(x[t,:], se[n,:]) / 32
// grid 1024 blocks x 16 tokens (4 tokens/wave). se L2-resident, direct loads.
__global__ __launch_bounds__(256, 4) void k_logits(const float* __restrict__ x,
                                                   const float* __restrict__ se,
                                                   float* __restrict__ logits) {
  const int wave = threadIdx.x >> 6, lane = threadIdx.x & 63;
  const int t0 = blockIdx.x * 16 + wave * 4;   // 4 tokens per wave
  float acc[64];                                // acc[tt*16+n], all const-indexed
#pragma unroll
  for (int j = 0; j < 64; ++j) acc[j] = 0.f;
  for (int it = 0; it < 4; ++it) {
    const int d = it * 256 + lane * 4;
    float4 xv[4];
#pragma unroll
    for (int tt = 0; tt < 4; ++tt)
      xv[tt] = ld4(x + (size_t)(t0 + tt) * ND + d);
#pragma unroll
    for (int n = 0; n < NS; ++n) {
      const float4 sv = ld4(se + (size_t)n * ND + d);
#pragma unroll
      for (int tt = 0; tt < 4; ++tt) {
        acc[tt * 16 + n] += xv[tt].x * sv.x + xv[tt].y * sv.y +
                            xv[tt].z * sv.z + xv[tt].w * sv.w;
      }
    }
  }
  // halving butterfly: after 6 steps lane l holds full sum of value index l.
#pragma unroll
  for (int k = 0; k < 6; ++k) {
    const int dlt = 1 << k;
    const bool hi = (lane & dlt) != 0;
#pragma unroll
    for (int i = 0; i < (64 >> (k + 1)); ++i) {
      const float a = acc[2 * i], b = acc[2 * i + 1];
      const float send = hi ? a : b;
      const float recv = __shfl_xor(send, dlt, 64);
      acc[i] = (hi ? b : a) + recv;
    }
  }
  logits[(size_t)t0 * NS + lane] = acc[0] * 0.03125f;
}

// ---- stage B: per-(b,n) max & sumexp over T. grid NB*NS, block 256
__global__ __launch_bounds__(256) void k_softmax_stats(const float* __restrict__ logits,
                                                       float* __restrict__ stats) {
  int bn = blockIdx.x;
  int b = bn >> 4, n = bn & 15;
  __shared__ float red[256];
  const float* lp = logits + ((size_t)b * NT) * NS + n;
  float m = -1e30f;
  for (int t = threadIdx.x; t < NT; t += 256) m = fmaxf(m, lp[(size_t)t * NS]);
  red[threadIdx.x] = m; __syncthreads();
  for (int s = 128; s > 0; s >>= 1) {
    if (threadIdx.x < s) red[threadIdx.x] = fmaxf(red[threadIdx.x], red[threadIdx.x + s]);
    __syncthreads();
  }
  m = red[0]; __syncthreads();
  float sm = 0.f;
  for (int t = threadIdx.x; t < NT; t += 256) sm += expf(lp[(size_t)t * NS] - m);
  red[threadIdx.x] = sm; __syncthreads();
  for (int s = 128; s > 0; s >>= 1) {
    if (threadIdx.x < s) red[threadIdx.x] += red[threadIdx.x + s];
    __syncthreads();
  }
  if (threadIdx.x == 0) { stats[bn * 2] = m; stats[bn * 2 + 1] = red[0]; }
}

// ---- stage C: si_part[tc][b][n][d] = sum_{t in tc} dispatch[b][t][n] * x[b][t][d]
// grid (tc=64, b=4); ping-pong prefetch xv[2][8] keeps 8 loads in flight.
__global__ __launch_bounds__(256) void k_slot_in(const float* __restrict__ x,
                                                 const float* __restrict__ logits,
                                                 const float* __restrict__ stats,
                                                 float* __restrict__ si_part) {
  __shared__ float s_w[NS][64];  // [n][t] so inner loop reads float4 over t
  const int tc = blockIdx.x, b = blockIdx.y;
  const int t0 = tc * 64;
  for (int i = threadIdx.x; i < NS * 64; i += 256) {
    const int n = i >> 6, t = i & 63;
    const float m = stats[(b * NS + n) * 2], s1 = stats[(b * NS + n) * 2 + 1];
    s_w[n][t] = expf(logits[((size_t)b * NT + t0 + t) * NS + n] - m) / s1;
  }
  __syncthreads();
  float4 acc[NS];
#pragma unroll
  for (int n = 0; n < NS; ++n) acc[n] = make_float4(0.f, 0.f, 0.f, 0.f);
  const int d = threadIdx.x * 4;
  const float* xb = x + ((size_t)b * NT + t0) * ND + d;
  float4 xv[2][8];
#pragma unroll
  for (int k = 0; k < 8; ++k) xv[0][k] = ld4(xb + (size_t)k * ND);
#pragma unroll
  for (int g = 0; g < 8; ++g) {          // t-group g covers t = g*8 .. g*8+7
    const int cur = g & 1;
    if (g < 7) {
#pragma unroll
      for (int k = 0; k < 8; ++k)
        xv[cur ^ 1][k] = ld4(xb + (size_t)((g + 1) * 8 + k) * ND);
    }
#pragma unroll
    for (int n = 0; n < NS; ++n) {
      const float4 w0 = ld4(&s_w[n][g * 8]);
      const float4 w1 = ld4(&s_w[n][g * 8 + 4]);
      fma4(acc[n], w0.x, xv[cur][0]); fma4(acc[n], w0.y, xv[cur][1]);
      fma4(acc[n], w0.z, xv[cur][2]); fma4(acc[n], w0.w, xv[cur][3]);
      fma4(acc[n], w1.x, xv[cur][4]); fma4(acc[n], w1.y, xv[cur][5]);
      fma4(acc[n], w1.z, xv[cur][6]); fma4(acc[n], w1.w, xv[cur][7]);
    }
  }
#pragma unroll
  for (int n = 0; n < NS; ++n)
    *reinterpret_cast<float4*>(si_part + (((size_t)tc * 4 + b) * NS + n) * ND + d) = acc[n];
}

// ---- stage C2+D fused: slot_in row = LayerNorm(sum_tc si_part[tc][row][:]).
// grid 64 rows x 1024 threads (thread <-> one d).
__global__ __launch_bounds__(1024) void k_reduce_si_ln(const float* __restrict__ si_part,
                                                       const float* __restrict__ gamma,
                                                       const float* __restrict__ beta,
                                                       float* __restrict__ h) {
  const int row = blockIdx.x;          // b*16 + n
  const int b = row >> 4, n = row & 15;
  const int d = threadIdx.x;
  float v = 0.f;
  for (int tc = 0; tc < 64; ++tc)
    v += si_part[(((size_t)tc * 4 + b) * NS + n) * ND + d];
  __shared__ float red[16];
  // ---- mean
  float s = v;
#pragma unroll
  for (int off = 32; off > 0; off >>= 1) s += __shfl_xor(s, off, 64);
  if ((threadIdx.x & 63) == 0) red[threadIdx.x >> 6] = s;
  __syncthreads();
  float mu = 0.f;
#pragma unroll
  for (int w = 0; w < 16; ++w) mu += red[w];
  mu *= (1.f / ND);
  __syncthreads();           // all reads of red done before re-writing
  // ---- variance
  const float q = v - mu;
  s = q * q;
#pragma unroll
  for (int off = 32; off > 0; off >>= 1) s += __shfl_xor(s, off, 64);
  if ((threadIdx.x & 63) == 0) red[threadIdx.x >> 6] = s;
  __syncthreads();
  float var = 0.f;
#pragma unroll
  for (int w = 0; w < 16; ++w) var += red[w];
  var *= (1.f / ND);
  const float rstd = rsqrtf(var + 1e-5f);
  h[(size_t)row * ND + d] = q * rstd * gamma[d] + beta[d];
}

// ---- stage E: u_part[dc][row][f] = h[row-chunk] @ W1-chunk (row=(b*NE+e)*2+s)
// grid (ft=4, dc=32, e=8) = 1024 blocks (4/CU, 16 waves/CU); K-chunk 32;
// ping-pong prefetch wv[2][4]. 256 threads, no register cap games.
__global__ __launch_bounds__(256, 4) void k_mlp1(const float* __restrict__ h,
                                                 const float* __restrict__ W1,
                                                 float* __restrict__ u_part) {
  __shared__ float s_h[32][8];  // [dd][j], j = b*2+s (1 KB)
  const int ft = blockIdx.x, dc = blockIdx.y, e = blockIdx.z;
  {
    const int dd = threadIdx.x >> 3, j = threadIdx.x & 7;
    const int b = j >> 1, s = j & 1;
    s_h[dd][j] = h[((size_t)b * NS + e * 2 + s) * ND + dc * 32 + dd];
  }
  __syncthreads();
  float4 acc[8];
#pragma unroll
  for (int j = 0; j < 8; ++j) acc[j] = make_float4(0.f, 0.f, 0.f, 0.f);
  const int f = ft * 1024 + threadIdx.x * 4;
  const float* wb = W1 + ((size_t)e * ND + dc * 32) * NF + f;
  float4 wv[2][4];
#pragma unroll
  for (int k = 0; k < 4; ++k) wv[0][k] = ld4(wb + (size_t)k * NF);
#pragma unroll
  for (int g = 0; g < 8; ++g) {         // K-chunk 32 = 8 groups of 4
    const int cur = g & 1;
    if (g < 7) {
#pragma unroll
      for (int k = 0; k < 4; ++k)
        wv[cur ^ 1][k] = ld4(wb + (size_t)((g + 1) * 4 + k) * NF);
    }
#pragma unroll
    for (int k = 0; k < 4; ++k) {
      const int dd = g * 4 + k;
      const float4 h0 = ld4(&s_h[dd][0]);
      const float4 h1 = ld4(&s_h[dd][4]);
      fma4(acc[0], h0.x, wv[cur][k]); fma4(acc[1], h0.y, wv[cur][k]);
      fma4(acc[2], h0.z, wv[cur][k]); fma4(acc[3], h0.w, wv[cur][k]);
      fma4(acc[4], h1.x, wv[cur][k]); fma4(acc[5], h1.y, wv[cur][k]);
      fma4(acc[6], h1.z, wv[cur][k]); fma4(acc[7], h1.w, wv[cur][k]);
    }
  }
#pragma unroll
  for (int j = 0; j < 8; ++j) {
    const int b = j >> 1, s = j & 1;
    const size_t row = ((size_t)b * NE + e) * 2 + s;
    *reinterpret_cast<float4*>(u_part + ((size_t)dc * 64 + row) * NF + f) = acc[j];
  }
}

// ---- stage F: so_part[fc][row][d] = gelu(sum_dc u_part)[row-chunk] @ W2-chunk
// grid (fc=128, e=8) = 1024 blocks; staging fuses the dc-reduction + gelu
// (each u element consumed by exactly one block); K-chunk 32; ping-pong wv[2][4].
__global__ __launch_bounds__(256, 4) void k_mlp2(const float* __restrict__ u_part,
                                                 const float* __restrict__ W2,
                                                 float* __restrict__ so_part) {
  __shared__ float s_u[32][8];  // [ff][j] (1 KB)
  const int fc = blockIdx.x, e = blockIdx.y;
  {
    const int j = threadIdx.x >> 5, ff = threadIdx.x & 31;  // coalesced over ff
    const int b = j >> 1, s = j & 1;
    const size_t urow = ((size_t)b * NE + e) * 2 + s;
    float sum = 0.f;
    for (int dcc = 0; dcc < 32; ++dcc)
      sum += u_part[((size_t)dcc * 64 + urow) * NF + fc * 32 + ff];
    s_u[ff][j] = gelu(sum);
  }
  __syncthreads();
  float4 acc[8];
#pragma unroll
  for (int j = 0; j < 8; ++j) acc[j] = make_float4(0.f, 0.f, 0.f, 0.f);
  const int d = threadIdx.x * 4;
  const float* wb = W2 + ((size_t)e * NF + fc * 32) * ND + d;
  float4 wv[2][4];
#pragma unroll
  for (int k = 0; k < 4; ++k) wv[0][k] = ld4(wb + (size_t)k * ND);
#pragma unroll
  for (int g = 0; g < 8; ++g) {
    const int cur = g & 1;
    if (g < 7) {
#pragma unroll
      for (int k = 0; k < 4; ++k)
        wv[cur ^ 1][k] = ld4(wb + (size_t)((g + 1) * 4 + k) * ND);
    }
#pragma unroll
    for (int k = 0; k < 4; ++k) {
      const int ff = g * 4 + k;
      const float4 u0 = ld4(&s_u[ff][0]);
      const float4 u1 = ld4(&s_u[ff][4]);
      fma4(acc[0], u0.x, wv[cur][k]); fma4(acc[1], u0.y, wv[cur][k]);
      fma4(acc[2], u0.z, wv[cur][k]); fma4(acc[3], u0.w, wv[cur][k]);
      fma4(acc[4], u1.x, wv[cur][k]); fma4(acc[5], u1.y, wv[cur][k]);
      fma4(acc[6], u1.z, wv[cur][k]); fma4(acc[7], u1.w, wv[cur][k]);
    }
  }
#pragma unroll
  for (int j = 0; j < 8; ++j) {
    const int b = j >> 1, s = j & 1;
    const size_t row = (size_t)b * NS + e * 2 + s;   // slot_out row order b*16+n
    *reinterpret_cast<float4*>(so_part + ((size_t)fc * 64 + row) * ND + d) = acc[j];
  }
}

// ---- stage F2: slot_out[i] = sum_fc so_part[fc][i]. grid 256, block 256
__global__ __launch_bounds__(256) void k_reduce_so(const float* __restrict__ so_part,
                                                   float* __restrict__ slot_out) {
  const int i = blockIdx.x * 256 + threadIdx.x;  // [0, 65536)
  float sum = 0.f;
  for (int fc = 0; fc < 128; ++fc)
    sum += so_part[(size_t)fc * 65536 + i];
  slot_out[i] = sum;
}

// ---- stage G: combine softmax over 16 slots + weighted sum.
// grid (tb=64, b=4); slot_out[b] staged in LDS (64KB); wave owns 16 tokens.
__global__ __launch_bounds__(256) void k_combine(const float* __restrict__ logits,
                                                 const float* __restrict__ slot_out,
                                                 float* __restrict__ out) {
  __shared__ float s_so[NS * ND];  // [n][d], 64 KB
  const int tb = blockIdx.x, b = blockIdx.y;
  for (int i = threadIdx.x; i < NS * ND; i += 256)
    s_so[i] = slot_out[(size_t)b * NS * ND + i];
  __syncthreads();
  const int wave = threadIdx.x >> 6, lane = threadIdx.x & 63;
  const int tbase = tb * 64 + wave * 16;
  for (int g = 0; g < 4; ++g) {
    const int t0 = tbase + g * 4;  // token within batch
    float c[4][NS];
#pragma unroll
    for (int tt = 0; tt < 4; ++tt) {
      const float* lp = logits + ((size_t)b * NT + t0 + tt) * NS;
      float l[NS];
      float m = -1e30f;
#pragma unroll
      for (int n = 0; n < NS; ++n) { l[n] = lp[n]; m = fmaxf(m, l[n]); }
      float s = 0.f;
#pragma unroll
      for (int n = 0; n < NS; ++n) { l[n] = expf(l[n] - m); s += l[n]; }
      const float rs = 1.f / s;
#pragma unroll
      for (int n = 0; n < NS; ++n) c[tt][n] = l[n] * rs;
    }
#pragma unroll
    for (int it = 0; it < 4; ++it) {
      const int d = it * 256 + lane * 4;
      float4 acc[4];
#pragma unroll
      for (int tt = 0; tt < 4; ++tt) acc[tt] = make_float4(0.f, 0.f, 0.f, 0.f);
#pragma unroll
      for (int n = 0; n < NS; ++n) {
        const float4 sv = ld4(&s_so[n * ND + d]);
        fma4(acc[0], c[0][n], sv); fma4(acc[1], c[1][n], sv);
        fma4(acc[2], c[2][n], sv); fma4(acc[3], c[3][n], sv);
      }
#pragma unroll
      for (int tt = 0; tt < 4; ++tt)
        *reinterpret_cast<float4*>(out + ((size_t)b * NT + t0 + tt) * ND + d) = acc[tt];
    }
  }
}

extern "C" void kernel_launch(void* const* d_in, const int* in_sizes, int n_in,
                              void* d_out, int out_size, void* d_ws, size_t ws_size,
                              hipStream_t stream) {
  const float* x     = (const float*)d_in[0];
  const float* se    = (const float*)d_in[1];
  const float* W1    = (const float*)d_in[2];
  const float* W2    = (const float*)d_in[3];
  const float* gamma = (const float*)d_in[4];
  const float* beta  = (const float*)d_in[5];
  float* out = (float*)d_out;

  // workspace layout (floats); everything fully written before read -> no zeroing.
  float* ws       = (float*)d_ws;
  float* logits   = ws;                   // 262,144          (1 MB)
  float* stats    = ws + 262144;          // 128 (pad 256)
  float* slot_in  = ws + 262400;          // 65,536           (h after fused LN)
  float* slot_out = ws + 327936;          // 65,536
  float* si_part  = ws + 393472;          // 4,194,304        (16 MB)
  float* u_part   = ws + 4587776;         // 8,388,608        (32 MB)
  float* so_part  = ws + 12976384;        // 8,388,608        (32 MB)

  k_logits<<<1024, 256, 0, stream>>>(x, se, logits);
  k_softmax_stats<<<NB * NS, 256, 0, stream>>>(logits, stats);
  k_slot_in<<<dim3(64, NB), 256, 0, stream>>>(x, logits, stats, si_part);
  k_reduce_si_ln<<<64, 1024, 0, stream>>>(si_part, gamma, beta, slot_in);
  k_mlp1<<<dim3(4, 32, NE), 256, 0, stream>>>(slot_in, W1, u_part);
  k_mlp2<<<dim3(128, NE), 256, 0, stream>>>(u_part, W2, so_part);
  k_reduce_so<<<256, 256, 0, stream>>>(so_part, slot_out);
  k_combine<<<dim3(64, NB), 256, 0, stream>>>(logits, slot_out, out);
}

// Round 4
// 448.227 us; speedup vs baseline: 1.0725x; 1.0725x over previous
//
#include <hip/hip_runtime.h>
#include <math.h>

#define NB 4
#define NT 4096
#define ND 1024
#define NS 16     // NUM_EXPERTS * NUM_SLOTS
#define NE 8
#define NF 4096

typedef float f32x4 __attribute__((ext_vector_type(4)));

__device__ __forceinline__ float gelu(float v) {
  return 0.5f * v * (1.f + erff(v * 0.70710678118654752f));
}
__device__ __forceinline__ void fma4(float4& a, float s, const float4& v) {
  a.x += s * v.x; a.y += s * v.y; a.z += s * v.z; a.w += s * v.w;
}
__device__ __forceinline__ float4 ld4(const float* p) {
  return *reinterpret_cast<const float4*>(p);
}
// nontemporal load for stream-once weight data (no L2/L3 victim churn)
__device__ __forceinline__ float4 ld4nt(const float* p) {
  f32x4 v = __builtin_nontemporal_load(reinterpret_cast<const f32x4*>(p));
  return make_float4(v[0], v[1], v[2], v[3]);
}

// ---- stage A: logits[t][n] = dot(x[t,:], se[n,:]) / 32
// grid 1024 blocks x 16 tokens (4 tokens/wave). se L2-resident, direct loads.
__global__ __launch_bounds__(256, 4) void k_logits(const float* __restrict__ x,
                                                   const float* __restrict__ se,
                                                   float* __restrict__ logits) {
  const int wave = threadIdx.x >> 6, lane = threadIdx.x & 63;
  const int t0 = blockIdx.x * 16 + wave * 4;   // 4 tokens per wave
  float acc[64];                                // acc[tt*16+n], all const-indexed
#pragma unroll
  for (int j = 0; j < 64; ++j) acc[j] = 0.f;
  for (int it = 0; it < 4; ++it) {
    const int d = it * 256 + lane * 4;
    float4 xv[4];
#pragma unroll
    for (int tt = 0; tt < 4; ++tt)
      xv[tt] = ld4(x + (size_t)(t0 + tt) * ND + d);
#pragma unroll
    for (int n = 0; n < NS; ++n) {
      const float4 sv = ld4(se + (size_t)n * ND + d);
#pragma unroll
      for (int tt = 0; tt < 4; ++tt) {
        acc[tt * 16 + n] += xv[tt].x * sv.x + xv[tt].y * sv.y +
                            xv[tt].z * sv.z + xv[tt].w * sv.w;
      }
    }
  }
  // halving butterfly: after 6 steps lane l holds full sum of value index l.
#pragma unroll
  for (int k = 0; k < 6; ++k) {
    const int dlt = 1 << k;
    const bool hi = (lane & dlt) != 0;
#pragma unroll
    for (int i = 0; i < (64 >> (k + 1)); ++i) {
      const float a = acc[2 * i], b = acc[2 * i + 1];
      const float send = hi ? a : b;
      const float recv = __shfl_xor(send, dlt, 64);
      acc[i] = (hi ? b : a) + recv;
    }
  }
  logits[(size_t)t0 * NS + lane] = acc[0] * 0.03125f;
}

// ---- stage B: per-(b,n) max & sumexp over T. grid NB*NS, block 256
__global__ __launch_bounds__(256) void k_softmax_stats(const float* __restrict__ logits,
                                                       float* __restrict__ stats) {
  int bn = blockIdx.x;
  int b = bn >> 4, n = bn & 15;
  __shared__ float red[256];
  const float* lp = logits + ((size_t)b * NT) * NS + n;
  float m = -1e30f;
  for (int t = threadIdx.x; t < NT; t += 256) m = fmaxf(m, lp[(size_t)t * NS]);
  red[threadIdx.x] = m; __syncthreads();
  for (int s = 128; s > 0; s >>= 1) {
    if (threadIdx.x < s) red[threadIdx.x] = fmaxf(red[threadIdx.x], red[threadIdx.x + s]);
    __syncthreads();
  }
  m = red[0]; __syncthreads();
  float sm = 0.f;
  for (int t = threadIdx.x; t < NT; t += 256) sm += expf(lp[(size_t)t * NS] - m);
  red[threadIdx.x] = sm; __syncthreads();
  for (int s = 128; s > 0; s >>= 1) {
    if (threadIdx.x < s) red[threadIdx.x] += red[threadIdx.x + s];
    __syncthreads();
  }
  if (threadIdx.x == 0) { stats[bn * 2] = m; stats[bn * 2 + 1] = red[0]; }
}

// ---- stage C: si_part[tc][b][n][d] = sum_{t in tc} dispatch[b][t][n] * x[b][t][d]
// grid (tc=64, b=4); ping-pong prefetch xv[2][8] keeps 8 loads in flight.
__global__ __launch_bounds__(256) void k_slot_in(const float* __restrict__ x,
                                                 const float* __restrict__ logits,
                                                 const float* __restrict__ stats,
                                                 float* __restrict__ si_part) {
  __shared__ float s_w[NS][64];  // [n][t] so inner loop reads float4 over t
  const int tc = blockIdx.x, b = blockIdx.y;
  const int t0 = tc * 64;
  for (int i = threadIdx.x; i < NS * 64; i += 256) {
    const int n = i >> 6, t = i & 63;
    const float m = stats[(b * NS + n) * 2], s1 = stats[(b * NS + n) * 2 + 1];
    s_w[n][t] = expf(logits[((size_t)b * NT + t0 + t) * NS + n] - m) / s1;
  }
  __syncthreads();
  float4 acc[NS];
#pragma unroll
  for (int n = 0; n < NS; ++n) acc[n] = make_float4(0.f, 0.f, 0.f, 0.f);
  const int d = threadIdx.x * 4;
  const float* xb = x + ((size_t)b * NT + t0) * ND + d;
  float4 xv[2][8];
#pragma unroll
  for (int k = 0; k < 8; ++k) xv[0][k] = ld4(xb + (size_t)k * ND);
#pragma unroll
  for (int g = 0; g < 8; ++g) {          // t-group g covers t = g*8 .. g*8+7
    const int cur = g & 1;
    if (g < 7) {
#pragma unroll
      for (int k = 0; k < 8; ++k)
        xv[cur ^ 1][k] = ld4(xb + (size_t)((g + 1) * 8 + k) * ND);
    }
#pragma unroll
    for (int n = 0; n < NS; ++n) {
      const float4 w0 = ld4(&s_w[n][g * 8]);
      const float4 w1 = ld4(&s_w[n][g * 8 + 4]);
      fma4(acc[n], w0.x, xv[cur][0]); fma4(acc[n], w0.y, xv[cur][1]);
      fma4(acc[n], w0.z, xv[cur][2]); fma4(acc[n], w0.w, xv[cur][3]);
      fma4(acc[n], w1.x, xv[cur][4]); fma4(acc[n], w1.y, xv[cur][5]);
      fma4(acc[n], w1.z, xv[cur][6]); fma4(acc[n], w1.w, xv[cur][7]);
    }
  }
#pragma unroll
  for (int n = 0; n < NS; ++n)
    *reinterpret_cast<float4*>(si_part + (((size_t)tc * 4 + b) * NS + n) * ND + d) = acc[n];
}

// ---- stage C2: slot_in[row][d] = sum_tc si_part[tc][row][d]. grid 256, block 256
__global__ __launch_bounds__(256) void k_reduce_si(const float* __restrict__ si_part,
                                                   float* __restrict__ slot_in) {
  const int i = blockIdx.x * 256 + threadIdx.x;  // i in [0, 65536)
  const int row = i >> 10, d = i & 1023;         // row = b*16+n
  const int b = row >> 4, n = row & 15;
  float sum = 0.f;
  for (int tc = 0; tc < 64; ++tc)
    sum += si_part[(((size_t)tc * 4 + b) * NS + n) * ND + d];
  slot_in[i] = sum;
}

// ---- stage D: LayerNorm over D, IN-PLACE. grid NB*NS rows, block 256
__global__ __launch_bounds__(256) void k_layernorm(float* __restrict__ slot_in,
                                                   const float* __restrict__ gamma,
                                                   const float* __restrict__ beta) {
  int row = blockIdx.x;
  __shared__ float red[256];
  float* rp = slot_in + (size_t)row * ND;
  float v[4];
  float sum = 0.f;
#pragma unroll
  for (int j = 0; j < 4; ++j) { v[j] = rp[threadIdx.x + j * 256]; sum += v[j]; }
  red[threadIdx.x] = sum; __syncthreads();
  for (int s = 128; s > 0; s >>= 1) {
    if (threadIdx.x < s) red[threadIdx.x] += red[threadIdx.x + s];
    __syncthreads();
  }
  float mu = red[0] * (1.f / ND); __syncthreads();
  float vs = 0.f;
#pragma unroll
  for (int j = 0; j < 4; ++j) { float t = v[j] - mu; vs += t * t; }
  red[threadIdx.x] = vs; __syncthreads();
  for (int s = 128; s > 0; s >>= 1) {
    if (threadIdx.x < s) red[threadIdx.x] += red[threadIdx.x + s];
    __syncthreads();
  }
  float rstd = rsqrtf(red[0] * (1.f / ND) + 1e-5f);
#pragma unroll
  for (int j = 0; j < 4; ++j) {
    int dd = threadIdx.x + j * 256;
    rp[dd] = (v[j] - mu) * rstd * gamma[dd] + beta[dd];
  }
}

// ---- stage E: u_part[dc][row][f] = h[row-chunk] @ W1-chunk (row=(b*NE+e)*2+s)
// grid (ft=4, dc=16, e=8) = 512 blocks; K-chunk 64; depth-8 ping-pong prefetch;
// nontemporal loads on the W1 stream (read-once).
__global__ __launch_bounds__(256) void k_mlp1(const float* __restrict__ h,
                                              const float* __restrict__ W1,
                                              float* __restrict__ u_part) {
  __shared__ float s_h[64][8];  // [dd][j], j = b*2+s
  const int ft = blockIdx.x, dc = blockIdx.y, e = blockIdx.z;
  for (int i = threadIdx.x; i < 512; i += 256) {
    const int dd = i >> 3, j = i & 7;
    const int b = j >> 1, s = j & 1;
    s_h[dd][j] = h[((size_t)b * NS + e * 2 + s) * ND + dc * 64 + dd];
  }
  __syncthreads();
  float4 acc[8];
#pragma unroll
  for (int j = 0; j < 8; ++j) acc[j] = make_float4(0.f, 0.f, 0.f, 0.f);
  const int f = ft * 1024 + threadIdx.x * 4;
  const float* wb = W1 + ((size_t)e * ND + dc * 64) * NF + f;
  float4 wv[2][8];
#pragma unroll
  for (int k = 0; k < 8; ++k) wv[0][k] = ld4nt(wb + (size_t)k * NF);
#pragma unroll
  for (int g = 0; g < 8; ++g) {          // K-chunk 64 = 8 groups of 8
    const int cur = g & 1;
    if (g < 7) {
#pragma unroll
      for (int k = 0; k < 8; ++k)
        wv[cur ^ 1][k] = ld4nt(wb + (size_t)((g + 1) * 8 + k) * NF);
    }
#pragma unroll
    for (int k = 0; k < 8; ++k) {
      const int dd = g * 8 + k;
      const float4 h0 = ld4(&s_h[dd][0]);
      const float4 h1 = ld4(&s_h[dd][4]);
      fma4(acc[0], h0.x, wv[cur][k]); fma4(acc[1], h0.y, wv[cur][k]);
      fma4(acc[2], h0.z, wv[cur][k]); fma4(acc[3], h0.w, wv[cur][k]);
      fma4(acc[4], h1.x, wv[cur][k]); fma4(acc[5], h1.y, wv[cur][k]);
      fma4(acc[6], h1.z, wv[cur][k]); fma4(acc[7], h1.w, wv[cur][k]);
    }
  }
#pragma unroll
  for (int j = 0; j < 8; ++j) {
    const int b = j >> 1, s = j & 1;
    const size_t row = ((size_t)b * NE + e) * 2 + s;
    *reinterpret_cast<float4*>(u_part + ((size_t)dc * 64 + row) * NF + f) = acc[j];
  }
}

// ---- stage F: so_part[fc][row][d] = gelu(sum_dc u_part)[row-chunk] @ W2-chunk
// grid (fc=64, e=8) = 512 blocks; staging fuses dc-reduction + gelu (replaces
// k_reduce_gelu); K-chunk 64; depth-8 ping-pong; nt loads on W2 stream.
__global__ __launch_bounds__(256) void k_mlp2(const float* __restrict__ u_part,
                                              const float* __restrict__ W2,
                                              float* __restrict__ so_part) {
  __shared__ float s_u[64][8];  // [ff][j]
  const int fc = blockIdx.x, e = blockIdx.y;
  for (int i = threadIdx.x; i < 512; i += 256) {
    const int j = i >> 6, ff = i & 63;     // ff fast -> coalesced over threads
    const int b = j >> 1, s = j & 1;
    const size_t urow = ((size_t)b * NE + e) * 2 + s;
    float sum = 0.f;
    for (int dcc = 0; dcc < 16; ++dcc)
      sum += u_part[((size_t)dcc * 64 + urow) * NF + fc * 64 + ff];
    s_u[ff][j] = gelu(sum);
  }
  __syncthreads();
  float4 acc[8];
#pragma unroll
  for (int j = 0; j < 8; ++j) acc[j] = make_float4(0.f, 0.f, 0.f, 0.f);
  const int d = threadIdx.x * 4;
  const float* wb = W2 + ((size_t)e * NF + fc * 64) * ND + d;
  float4 wv[2][8];
#pragma unroll
  for (int k = 0; k < 8; ++k) wv[0][k] = ld4nt(wb + (size_t)k * ND);
#pragma unroll
  for (int g = 0; g < 8; ++g) {
    const int cur = g & 1;
    if (g < 7) {
#pragma unroll
      for (int k = 0; k < 8; ++k)
        wv[cur ^ 1][k] = ld4nt(wb + (size_t)((g + 1) * 8 + k) * ND);
    }
#pragma unroll
    for (int k = 0; k < 8; ++k) {
      const int ff = g * 8 + k;
      const float4 u0 = ld4(&s_u[ff][0]);
      const float4 u1 = ld4(&s_u[ff][4]);
      fma4(acc[0], u0.x, wv[cur][k]); fma4(acc[1], u0.y, wv[cur][k]);
      fma4(acc[2], u0.z, wv[cur][k]); fma4(acc[3], u0.w, wv[cur][k]);
      fma4(acc[4], u1.x, wv[cur][k]); fma4(acc[5], u1.y, wv[cur][k]);
      fma4(acc[6], u1.z, wv[cur][k]); fma4(acc[7], u1.w, wv[cur][k]);
    }
  }
#pragma unroll
  for (int j = 0; j < 8; ++j) {
    const int b = j >> 1, s = j & 1;
    const size_t row = (size_t)b * NS + e * 2 + s;   // slot_out row order b*16+n
    *reinterpret_cast<float4*>(so_part + ((size_t)fc * 64 + row) * ND + d) = acc[j];
  }
}

// ---- stage F2: slot_out[i] = sum_fc so_part[fc][i]. grid 256, block 256
__global__ __launch_bounds__(256) void k_reduce_so(const float* __restrict__ so_part,
                                                   float* __restrict__ slot_out) {
  const int i = blockIdx.x * 256 + threadIdx.x;  // [0, 65536)
  float sum = 0.f;
  for (int fc = 0; fc < 64; ++fc)
    sum += so_part[(size_t)fc * 65536 + i];
  slot_out[i] = sum;
}

// ---- stage G: combine softmax over 16 slots + weighted sum.
// grid (tb=64, b=4); slot_out[b] staged in LDS (64KB); wave owns 16 tokens.
__global__ __launch_bounds__(256) void k_combine(const float* __restrict__ logits,
                                                 const float* __restrict__ slot_out,
                                                 float* __restrict__ out) {
  __shared__ float s_so[NS * ND];  // [n][d], 64 KB
  const int tb = blockIdx.x, b = blockIdx.y;
  for (int i = threadIdx.x; i < NS * ND; i += 256)
    s_so[i] = slot_out[(size_t)b * NS * ND + i];
  __syncthreads();
  const int wave = threadIdx.x >> 6, lane = threadIdx.x & 63;
  const int tbase = tb * 64 + wave * 16;
  for (int g = 0; g < 4; ++g) {
    const int t0 = tbase + g * 4;  // token within batch
    float c[4][NS];
#pragma unroll
    for (int tt = 0; tt < 4; ++tt) {
      const float* lp = logits + ((size_t)b * NT + t0 + tt) * NS;
      float l[NS];
      float m = -1e30f;
#pragma unroll
      for (int n = 0; n < NS; ++n) { l[n] = lp[n]; m = fmaxf(m, l[n]); }
      float s = 0.f;
#pragma unroll
      for (int n = 0; n < NS; ++n) { l[n] = expf(l[n] - m); s += l[n]; }
      const float rs = 1.f / s;
#pragma unroll
      for (int n = 0; n < NS; ++n) c[tt][n] = l[n] * rs;
    }
#pragma unroll
    for (int it = 0; it < 4; ++it) {
      const int d = it * 256 + lane * 4;
      float4 acc[4];
#pragma unroll
      for (int tt = 0; tt < 4; ++tt) acc[tt] = make_float4(0.f, 0.f, 0.f, 0.f);
#pragma unroll
      for (int n = 0; n < NS; ++n) {
        const float4 sv = ld4(&s_so[n * ND + d]);
        fma4(acc[0], c[0][n], sv); fma4(acc[1], c[1][n], sv);
        fma4(acc[2], c[2][n], sv); fma4(acc[3], c[3][n], sv);
      }
#pragma unroll
      for (int tt = 0; tt < 4; ++tt)
        *reinterpret_cast<float4*>(out + ((size_t)b * NT + t0 + tt) * ND + d) = acc[tt];
    }
  }
}

extern "C" void kernel_launch(void* const* d_in, const int* in_sizes, int n_in,
                              void* d_out, int out_size, void* d_ws, size_t ws_size,
                              hipStream_t stream) {
  const float* x     = (const float*)d_in[0];
  const float* se    = (const float*)d_in[1];
  const float* W1    = (const float*)d_in[2];
  const float* W2    = (const float*)d_in[3];
  const float* gamma = (const float*)d_in[4];
  const float* beta  = (const float*)d_in[5];
  float* out = (float*)d_out;

  // workspace layout (floats); everything fully written before read -> no zeroing.
  float* ws       = (float*)d_ws;
  float* logits   = ws;                   // 262,144          (1 MB)
  float* stats    = ws + 262144;          // 128 (pad 256)
  float* slot_in  = ws + 262400;          // 65,536           (h after LN)
  float* slot_out = ws + 327936;          // 65,536
  float* si_part  = ws + 393472;          // 4,194,304        (16 MB)
  float* u_part   = ws + 4587776;         // 4,194,304        (16 MB)
  float* so_part  = ws + 8782080;         // 4,194,304        (16 MB)

  k_logits<<<1024, 256, 0, stream>>>(x, se, logits);
  k_softmax_stats<<<NB * NS, 256, 0, stream>>>(logits, stats);
  k_slot_in<<<dim3(64, NB), 256, 0, stream>>>(x, logits, stats, si_part);
  k_reduce_si<<<256, 256, 0, stream>>>(si_part, slot_in);
  k_layernorm<<<NB * NS, 256, 0, stream>>>(slot_in, gamma, beta);
  k_mlp1<<<dim3(4, 16, NE), 256, 0, stream>>>(slot_in, W1, u_part);
  k_mlp2<<<dim3(64, NE), 256, 0, stream>>>(u_part, W2, so_part);
  k_reduce_so<<<256, 256, 0, stream>>>(so_part, slot_out);
  k_combine<<<dim3(64, NB), 256, 0, stream>>>(logits, slot_out, out);
}